// Round 2
// baseline (1270.819 us; speedup 1.0000x reference)
//
#include <hip/hip_runtime.h>

// GCN layer on MI355X:
//   deg_out/deg_in from edge list (int atomics)
//   h = (features * deg_out^-1/2) @ W   (W in LDS, f32 vector ALU)
//   out[d] += h[s] for each edge        (f32 global atomics, 4/thread)
//   out = out * deg_in^-1/2 + bias

__global__ void degree_kernel(const int* __restrict__ src, const int* __restrict__ dst,
                              int* __restrict__ deg_out, int* __restrict__ deg_in,
                              int n_edges) {
    int idx = blockIdx.x * blockDim.x + threadIdx.x;
    int stride = gridDim.x * blockDim.x;
    for (int e = idx; e < n_edges; e += stride) {
        atomicAdd(&deg_out[src[e]], 1);
        atomicAdd(&deg_in[dst[e]], 1);
    }
}

// 16 nodes per 256-thread block; thread t -> node t/16, cols [(t%16)*4 .. +3]
__global__ __launch_bounds__(256) void gemm_kernel(
    const float* __restrict__ feat, const float* __restrict__ weight,
    const int* __restrict__ deg_out, float* __restrict__ h, int n_nodes) {
    __shared__ float W[64][64];  // 16 KB
    int t = threadIdx.x;
    {
        const float4* w4p = (const float4*)weight;   // 1024 float4s
        float4* W4 = (float4*)&W[0][0];
#pragma unroll
        for (int i = 0; i < 4; ++i) W4[t + 256 * i] = w4p[t + 256 * i];
    }
    __syncthreads();

    int n = blockIdx.x * 16 + (t >> 4);
    if (n >= n_nodes) return;
    int col4 = (t & 15) << 2;

    const float4* f4p = (const float4*)(feat + (size_t)n * 64);
    float accx = 0.f, accy = 0.f, accz = 0.f, accw = 0.f;
#pragma unroll
    for (int k4 = 0; k4 < 16; ++k4) {
        float4 f = f4p[k4];
#pragma unroll
        for (int kk = 0; kk < 4; ++kk) {
            int k = k4 * 4 + kk;
            float4 w = *(const float4*)&W[k][col4];
            float fv = (kk == 0) ? f.x : (kk == 1) ? f.y : (kk == 2) ? f.z : f.w;
            accx += fv * w.x;
            accy += fv * w.y;
            accz += fv * w.z;
            accw += fv * w.w;
        }
    }
    float s = rsqrtf((float)max(deg_out[n], 1));
    float4 r;
    r.x = accx * s; r.y = accy * s; r.z = accz * s; r.w = accw * s;
    *(float4*)(h + (size_t)n * 64 + col4) = r;
}

// one thread = one edge x 4 features; 16 threads cooperate on an edge's 64 cols
__global__ void scatter_kernel(const float* __restrict__ h, const int* __restrict__ src,
                               const int* __restrict__ dst, float* __restrict__ out,
                               int n_edges) {
    long long total = (long long)n_edges * 16;
    long long idx = (long long)blockIdx.x * blockDim.x + threadIdx.x;
    long long stride = (long long)gridDim.x * blockDim.x;
    for (long long i = idx; i < total; i += stride) {
        int e = (int)(i >> 4);
        int c4 = ((int)i & 15) << 2;
        int s = src[e];
        int d = dst[e];
        const float4 v = *(const float4*)(h + (size_t)s * 64 + c4);
        float* o = out + (size_t)d * 64 + c4;
        atomicAdd(o + 0, v.x);
        atomicAdd(o + 1, v.y);
        atomicAdd(o + 2, v.z);
        atomicAdd(o + 3, v.w);
    }
}

__global__ void finalize_kernel(float* __restrict__ out, const int* __restrict__ deg_in,
                                const float* __restrict__ bias, int n_nodes) {
    int total = n_nodes * 16;
    int idx = blockIdx.x * blockDim.x + threadIdx.x;
    int stride = gridDim.x * blockDim.x;
    for (int i = idx; i < total; i += stride) {
        int n = i >> 4;
        int c4 = (i & 15) << 2;
        float s = rsqrtf((float)max(deg_in[n], 1));
        float4 v = *(float4*)(out + (size_t)n * 64 + c4);
        float4 b = *(const float4*)(bias + c4);
        v.x = v.x * s + b.x;
        v.y = v.y * s + b.y;
        v.z = v.z * s + b.z;
        v.w = v.w * s + b.w;
        *(float4*)(out + (size_t)n * 64 + c4) = v;
    }
}

extern "C" void kernel_launch(void* const* d_in, const int* in_sizes, int n_in,
                              void* d_out, int out_size, void* d_ws, size_t ws_size,
                              hipStream_t stream) {
    const float* feat   = (const float*)d_in[0];
    const float* weight = (const float*)d_in[1];
    const float* bias   = (const float*)d_in[2];
    const int*   src    = (const int*)d_in[3];
    const int*   dst    = (const int*)d_in[4];
    int n_edges = in_sizes[3];
    int n_nodes = in_sizes[0] / 64;
    float* out = (float*)d_out;

    // workspace layout: deg_out[int N] | deg_in[int N] | h[float N*64]
    int* deg_out = (int*)d_ws;
    int* deg_in  = deg_out + n_nodes;
    float* h     = (float*)(deg_in + n_nodes);

    hipMemsetAsync(deg_out, 0, sizeof(int) * 2 * (size_t)n_nodes, stream);
    hipMemsetAsync(d_out, 0, sizeof(float) * (size_t)out_size, stream);

    degree_kernel<<<2048, 256, 0, stream>>>(src, dst, deg_out, deg_in, n_edges);
    gemm_kernel<<<(n_nodes + 15) / 16, 256, 0, stream>>>(feat, weight, deg_out, h, n_nodes);
    scatter_kernel<<<8192, 256, 0, stream>>>(h, src, dst, out, n_edges);
    finalize_kernel<<<2048, 256, 0, stream>>>(out, deg_in, bias, n_nodes);
}

// Round 4
// 514.158 us; speedup vs baseline: 2.4717x; 2.4717x over previous
//
#include <hip/hip_runtime.h>

// GCN layer on MI355X — CSR-gather formulation (no f32 atomics):
//   1. deg_out/deg_in from edge list (int atomics)
//   2. row_start = exclusive_scan(deg_in)  (single-block scan)
//   3. CSR fill via atomicSub cursor on deg_in
//   4. h = (features @ W) * deg_out^-1/2   (W in LDS)
//   5. out[n] = (sum_{s in csr[n]} h[s]) * deg_in^-1/2 + bias  (plain loads)

__global__ void degree_kernel(const int* __restrict__ src, const int* __restrict__ dst,
                              int* __restrict__ deg_out, int* __restrict__ deg_in,
                              int n_edges) {
    int idx = blockIdx.x * blockDim.x + threadIdx.x;
    int stride = gridDim.x * blockDim.x;
    for (int e = idx; e < n_edges; e += stride) {
        atomicAdd(&deg_out[src[e]], 1);
        atomicAdd(&deg_in[dst[e]], 1);
    }
}

// Exclusive prefix sum of deg[0..n) -> row_start[0..n], row_start[n]=total.
// Single workgroup, 1024 threads, chunk-serial + Hillis-Steele over partials.
__global__ __launch_bounds__(1024) void scan_kernel(const int* __restrict__ deg,
                                                    int* __restrict__ row_start, int n) {
    __shared__ int sums[1024];
    int t = threadIdx.x;
    int chunk = (n + 1023) >> 10;
    int beg = t * chunk;
    int end = min(beg + chunk, n);
    int local = 0;
    for (int i = beg; i < end; ++i) local += deg[i];
    sums[t] = local;
    __syncthreads();
    // inclusive scan over 1024 partials
    for (int off = 1; off < 1024; off <<= 1) {
        int v = (t >= off) ? sums[t - off] : 0;
        __syncthreads();
        sums[t] += v;
        __syncthreads();
    }
    int running = sums[t] - local;  // exclusive base for this chunk
    for (int i = beg; i < end; ++i) {
        row_start[i] = running;
        running += deg[i];
    }
    if (t == 1023) row_start[n] = sums[1023];
}

// Places src of each edge into its dst bucket. Consumes deg_in as cursor
// (leaves it zeroed); bucket fill order is reversed — irrelevant for a sum.
__global__ void csr_fill_kernel(const int* __restrict__ src, const int* __restrict__ dst,
                                const int* __restrict__ row_start, int* __restrict__ cursor,
                                int* __restrict__ csr_src, int n_edges) {
    int idx = blockIdx.x * blockDim.x + threadIdx.x;
    int stride = gridDim.x * blockDim.x;
    for (int e = idx; e < n_edges; e += stride) {
        int d = dst[e];
        int pos = atomicSub(&cursor[d], 1) - 1;
        csr_src[row_start[d] + pos] = src[e];
    }
}

// 16 nodes per 256-thread block; thread t -> node t/16, cols [(t%16)*4 .. +3]
__global__ __launch_bounds__(256) void gemm_kernel(
    const float* __restrict__ feat, const float* __restrict__ weight,
    const int* __restrict__ deg_out, float* __restrict__ h, int n_nodes) {
    __shared__ float W[64][64];  // 16 KB
    int t = threadIdx.x;
    {
        const float4* w4p = (const float4*)weight;   // 1024 float4s
        float4* W4 = (float4*)&W[0][0];
#pragma unroll
        for (int i = 0; i < 4; ++i) W4[t + 256 * i] = w4p[t + 256 * i];
    }
    __syncthreads();

    int n = blockIdx.x * 16 + (t >> 4);
    if (n >= n_nodes) return;
    int col4 = (t & 15) << 2;

    const float4* f4p = (const float4*)(feat + (size_t)n * 64);
    float accx = 0.f, accy = 0.f, accz = 0.f, accw = 0.f;
#pragma unroll
    for (int k4 = 0; k4 < 16; ++k4) {
        float4 f = f4p[k4];
#pragma unroll
        for (int kk = 0; kk < 4; ++kk) {
            int k = k4 * 4 + kk;
            float4 w = *(const float4*)&W[k][col4];
            float fv = (kk == 0) ? f.x : (kk == 1) ? f.y : (kk == 2) ? f.z : f.w;
            accx += fv * w.x;
            accy += fv * w.y;
            accz += fv * w.z;
            accw += fv * w.w;
        }
    }
    float s = rsqrtf((float)max(deg_out[n], 1));
    float4 r;
    r.x = accx * s; r.y = accy * s; r.z = accz * s; r.w = accw * s;
    *(float4*)(h + (size_t)n * 64 + col4) = r;
}

// One node per 16 threads; register float4 accumulation over CSR neighbors,
// fused deg_in^-1/2 scale + bias. Fully overwrites out.
__global__ __launch_bounds__(256) void aggregate_kernel(
    const float* __restrict__ h, const int* __restrict__ row_start,
    const int* __restrict__ csr_src, const float* __restrict__ bias,
    float* __restrict__ out, int n_nodes) {
    int t = threadIdx.x;
    int n = blockIdx.x * 16 + (t >> 4);
    if (n >= n_nodes) return;
    int c4 = (t & 15) << 2;

    int beg = row_start[n];
    int end = row_start[n + 1];
    float4 acc = make_float4(0.f, 0.f, 0.f, 0.f);
    for (int j = beg; j < end; ++j) {
        int s = csr_src[j];  // same addr across the 16 lanes -> broadcast
        float4 v = *(const float4*)(h + (size_t)s * 64 + c4);
        acc.x += v.x; acc.y += v.y; acc.z += v.z; acc.w += v.w;
    }
    float sc = rsqrtf((float)max(end - beg, 1));
    float4 b = *(const float4*)(bias + c4);
    float4 r;
    r.x = acc.x * sc + b.x;
    r.y = acc.y * sc + b.y;
    r.z = acc.z * sc + b.z;
    r.w = acc.w * sc + b.w;
    *(float4*)(out + (size_t)n * 64 + c4) = r;
}

extern "C" void kernel_launch(void* const* d_in, const int* in_sizes, int n_in,
                              void* d_out, int out_size, void* d_ws, size_t ws_size,
                              hipStream_t stream) {
    const float* feat   = (const float*)d_in[0];
    const float* weight = (const float*)d_in[1];
    const float* bias   = (const float*)d_in[2];
    const int*   src    = (const int*)d_in[3];
    const int*   dst    = (const int*)d_in[4];
    int n_edges = in_sizes[3];
    int n_nodes = in_sizes[0] / 64;
    float* out = (float*)d_out;

    // ws layout: deg_out[N] | deg_in[N] | row_start[N+1] | csr_src[E] | h[N*64 f32]
    int* deg_out   = (int*)d_ws;
    int* deg_in    = deg_out + n_nodes;
    int* row_start = deg_in + n_nodes;
    int* csr_src   = row_start + (n_nodes + 1);
    float* h       = (float*)(csr_src + n_edges);

    hipMemsetAsync(deg_out, 0, sizeof(int) * 2 * (size_t)n_nodes, stream);

    degree_kernel<<<2048, 256, 0, stream>>>(src, dst, deg_out, deg_in, n_edges);
    scan_kernel<<<1, 1024, 0, stream>>>(deg_in, row_start, n_nodes);
    csr_fill_kernel<<<2048, 256, 0, stream>>>(src, dst, row_start, deg_in, csr_src, n_edges);
    gemm_kernel<<<(n_nodes + 15) / 16, 256, 0, stream>>>(feat, weight, deg_out, h, n_nodes);
    aggregate_kernel<<<(n_nodes + 15) / 16, 256, 0, stream>>>(h, row_start, csr_src, bias, out, n_nodes);
}

// Round 7
// 350.544 us; speedup vs baseline: 3.6253x; 1.4667x over previous
//
#include <hip/hip_runtime.h>

// GCN layer on MI355X — CSR-gather formulation (no f32 atomics):
//   1. deg_out/deg_in from edge list (int atomics)
//   2. row_start = exclusive_scan(deg_in)  (3-phase grid-wide scan)
//   3. CSR fill via atomicSub cursor on deg_in
//   4. h = (features @ W) * deg_out^-1/2   (W in LDS)
//   5. out[n] = (sum_{s in csr[n]} h[s]) * deg_in^-1/2 + bias  (plain loads)

__global__ void degree_kernel(const int* __restrict__ src, const int* __restrict__ dst,
                              int* __restrict__ deg_out, int* __restrict__ deg_in,
                              int n_edges) {
    int idx = blockIdx.x * blockDim.x + threadIdx.x;
    int stride = gridDim.x * blockDim.x;
    for (int e = idx; e < n_edges; e += stride) {
        atomicAdd(&deg_out[src[e]], 1);
        atomicAdd(&deg_in[dst[e]], 1);
    }
}

// ---- 3-phase exclusive scan of deg[0..n) -> row_start[0..n] --------------
// phase 1: per-block (256-wide) tree reduce -> partials[b]
__global__ __launch_bounds__(256) void scan_reduce_kernel(const int* __restrict__ deg,
                                                          int* __restrict__ partials, int n) {
    __shared__ int sm[256];
    int t = threadIdx.x;
    int i = blockIdx.x * 256 + t;
    sm[t] = (i < n) ? deg[i] : 0;
    __syncthreads();
    for (int off = 128; off > 0; off >>= 1) {
        if (t < off) sm[t] += sm[t + off];
        __syncthreads();
    }
    if (t == 0) partials[blockIdx.x] = sm[0];
}

// phase 2: single block; exclusive-scan partials[0..nb) in place; partials[nb]=total
__global__ __launch_bounds__(1024) void scan_partials_kernel(int* __restrict__ partials, int nb) {
    __shared__ int sm[1024];
    int t = threadIdx.x;
    int chunk = (nb + 1023) >> 10;
    int beg = t * chunk;
    int end = min(beg + chunk, nb);
    int local = 0;
    for (int i = beg; i < end; ++i) local += partials[i];
    sm[t] = local;
    __syncthreads();
    for (int off = 1; off < 1024; off <<= 1) {
        int v = (t >= off) ? sm[t - off] : 0;
        __syncthreads();
        sm[t] += v;
        __syncthreads();
    }
    int running = sm[t] - local;  // exclusive base for this chunk
    for (int i = beg; i < end; ++i) {
        int d = partials[i];
        partials[i] = running;
        running += d;
    }
    if (t == 1023) partials[nb] = sm[1023];
}

// phase 3: per-block inclusive LDS scan + block base -> row_start; last writes total
__global__ __launch_bounds__(256) void scan_final_kernel(const int* __restrict__ deg,
                                                         const int* __restrict__ partials,
                                                         int* __restrict__ row_start, int n) {
    __shared__ int sm[256];
    int t = threadIdx.x;
    int i = blockIdx.x * 256 + t;
    int v = (i < n) ? deg[i] : 0;
    sm[t] = v;
    __syncthreads();
    for (int off = 1; off < 256; off <<= 1) {
        int u = (t >= off) ? sm[t - off] : 0;
        __syncthreads();
        sm[t] += u;
        __syncthreads();
    }
    int excl = sm[t] - v + partials[blockIdx.x];
    if (i < n) row_start[i] = excl;
    if (i == n - 1) row_start[n] = excl + v;
}
// --------------------------------------------------------------------------

// Places src of each edge into its dst bucket. Consumes deg_in as cursor
// (leaves it zeroed); bucket fill order is reversed — irrelevant for a sum.
__global__ void csr_fill_kernel(const int* __restrict__ src, const int* __restrict__ dst,
                                const int* __restrict__ row_start, int* __restrict__ cursor,
                                int* __restrict__ csr_src, int n_edges) {
    int idx = blockIdx.x * blockDim.x + threadIdx.x;
    int stride = gridDim.x * blockDim.x;
    for (int e = idx; e < n_edges; e += stride) {
        int d = dst[e];
        int pos = atomicSub(&cursor[d], 1) - 1;
        csr_src[row_start[d] + pos] = src[e];
    }
}

// 16 nodes per 256-thread block; thread t -> node t/16, cols [(t%16)*4 .. +3]
__global__ __launch_bounds__(256) void gemm_kernel(
    const float* __restrict__ feat, const float* __restrict__ weight,
    const int* __restrict__ deg_out, float* __restrict__ h, int n_nodes) {
    __shared__ float W[64][64];  // 16 KB
    int t = threadIdx.x;
    {
        const float4* w4p = (const float4*)weight;   // 1024 float4s
        float4* W4 = (float4*)&W[0][0];
#pragma unroll
        for (int i = 0; i < 4; ++i) W4[t + 256 * i] = w4p[t + 256 * i];
    }
    __syncthreads();

    int n = blockIdx.x * 16 + (t >> 4);
    if (n >= n_nodes) return;
    int col4 = (t & 15) << 2;

    const float4* f4p = (const float4*)(feat + (size_t)n * 64);
    float accx = 0.f, accy = 0.f, accz = 0.f, accw = 0.f;
#pragma unroll
    for (int k4 = 0; k4 < 16; ++k4) {
        float4 f = f4p[k4];
#pragma unroll
        for (int kk = 0; kk < 4; ++kk) {
            int k = k4 * 4 + kk;
            float4 w = *(const float4*)&W[k][col4];
            float fv = (kk == 0) ? f.x : (kk == 1) ? f.y : (kk == 2) ? f.z : f.w;
            accx += fv * w.x;
            accy += fv * w.y;
            accz += fv * w.z;
            accw += fv * w.w;
        }
    }
    float s = rsqrtf((float)max(deg_out[n], 1));
    float4 r;
    r.x = accx * s; r.y = accy * s; r.z = accz * s; r.w = accw * s;
    *(float4*)(h + (size_t)n * 64 + col4) = r;
}

// One node per 16 threads; register float4 accumulation over CSR neighbors,
// fused deg_in^-1/2 scale + bias. Fully overwrites out.
__global__ __launch_bounds__(256) void aggregate_kernel(
    const float* __restrict__ h, const int* __restrict__ row_start,
    const int* __restrict__ csr_src, const float* __restrict__ bias,
    float* __restrict__ out, int n_nodes) {
    int t = threadIdx.x;
    int n = blockIdx.x * 16 + (t >> 4);
    if (n >= n_nodes) return;
    int c4 = (t & 15) << 2;

    int beg = row_start[n];
    int end = row_start[n + 1];
    float4 acc = make_float4(0.f, 0.f, 0.f, 0.f);
    for (int j = beg; j < end; ++j) {
        int s = csr_src[j];  // same addr across the 16 lanes -> broadcast
        float4 v = *(const float4*)(h + (size_t)s * 64 + c4);
        acc.x += v.x; acc.y += v.y; acc.z += v.z; acc.w += v.w;
    }
    float sc = rsqrtf((float)max(end - beg, 1));
    float4 b = *(const float4*)(bias + c4);
    float4 r;
    r.x = acc.x * sc + b.x;
    r.y = acc.y * sc + b.y;
    r.z = acc.z * sc + b.z;
    r.w = acc.w * sc + b.w;
    *(float4*)(out + (size_t)n * 64 + c4) = r;
}

extern "C" void kernel_launch(void* const* d_in, const int* in_sizes, int n_in,
                              void* d_out, int out_size, void* d_ws, size_t ws_size,
                              hipStream_t stream) {
    const float* feat   = (const float*)d_in[0];
    const float* weight = (const float*)d_in[1];
    const float* bias   = (const float*)d_in[2];
    const int*   src    = (const int*)d_in[3];
    const int*   dst    = (const int*)d_in[4];
    int n_edges = in_sizes[3];
    int n_nodes = in_sizes[0] / 64;
    float* out = (float*)d_out;

    int nb = (n_nodes + 255) / 256;  // scan blocks

    // ws layout: deg_out[N] | deg_in[N] | row_start[N+1] | partials[nb+1] | csr_src[E] | h[N*64 f32]
    int* deg_out   = (int*)d_ws;
    int* deg_in    = deg_out + n_nodes;
    int* row_start = deg_in + n_nodes;
    int* partials  = row_start + (n_nodes + 1);
    int* csr_src   = partials + (nb + 1);
    float* h       = (float*)(csr_src + n_edges);

    hipMemsetAsync(deg_out, 0, sizeof(int) * 2 * (size_t)n_nodes, stream);

    degree_kernel<<<2048, 256, 0, stream>>>(src, dst, deg_out, deg_in, n_edges);
    scan_reduce_kernel<<<nb, 256, 0, stream>>>(deg_in, partials, n_nodes);
    scan_partials_kernel<<<1, 1024, 0, stream>>>(partials, nb);
    scan_final_kernel<<<nb, 256, 0, stream>>>(deg_in, partials, row_start, n_nodes);
    csr_fill_kernel<<<2048, 256, 0, stream>>>(src, dst, row_start, deg_in, csr_src, n_edges);
    gemm_kernel<<<(n_nodes + 15) / 16, 256, 0, stream>>>(feat, weight, deg_out, h, n_nodes);
    aggregate_kernel<<<(n_nodes + 15) / 16, 256, 0, stream>>>(h, row_start, csr_src, bias, out, n_nodes);
}